// Round 13
// baseline (31.779 us; speedup 1.0000x reference)
//
#include <hip/hip_runtime.h>

typedef float f32x4 __attribute__((ext_vector_type(4)));

// Problem constants: x [B,C,T] fp32 -> out [B,C,T] fp32.
#define B_ 32
#define C_ 256
#define T_ 2048

// R5:  plain stores (L2 write-combining), never nontemporal.
// R7:  strided global loads cap ~2.6 TB/s -> coalesced staging only.
// R8:  XOR-swizzled b128 LDS reads conflict-free.
// R10: coalesced stores via LDS round-trip: 40->31 us.
// R11/R12: LDS-double-buffered pipelining ~neutral at 8-9 waves/CU; residency
//   pinned ~9 waves/CU across LDS configs -> suspect gload_lds DMA queue +
//   16 KiB/wave. R13: single 8 KiB buffer/wave, NR=2, row 1 reg-staged
//   (T14) -> 16 waves/CU target, gload_lds only for row 0.

#define STEP(X0, XP1, O) { \
    float y = w0 * xm1;  y = y + w1 * (X0);  y = y + w2 * (XP1); \
    y = y + bb;  y = y * inv;  y = y + add; \
    float dv = (y - v) * 0.5f;  v = v + dv; \
    float s = (v >= 1.0f) ? 1.0f : 0.0f; \
    (O) = s + (X0); \
    v = (v >= 1.0f) ? 0.0f : v; \
    xm1 = (X0); }

#define Q4(BV, NX, O) \
    STEP(BV.x, BV.y, O.x) STEP(BV.y, BV.z, O.y) \
    STEP(BV.z, BV.w, O.z) STEP(BV.w, NX,   O.w)

#define LDPH(p0,p1,p2,p3,p4,p5,p6,p7, GC) { \
    const int _m = ((GC) >> 3) & 7; \
    const float* _bp = wl + ((GC) << 2); \
    p0 = *(const f32x4*)(_bp + ((0 ^ _m) << 2)); \
    p1 = *(const f32x4*)(_bp + ((1 ^ _m) << 2)); \
    p2 = *(const f32x4*)(_bp + ((2 ^ _m) << 2)); \
    p3 = *(const f32x4*)(_bp + ((3 ^ _m) << 2)); \
    p4 = *(const f32x4*)(_bp + ((4 ^ _m) << 2)); \
    p5 = *(const f32x4*)(_bp + ((5 ^ _m) << 2)); \
    p6 = *(const f32x4*)(_bp + ((6 ^ _m) << 2)); \
    p7 = *(const f32x4*)(_bp + ((7 ^ _m) << 2)); }

#define PHC(r0,r1,r2,r3,r4,r5,r6,r7, PEEK) { \
    f32x4 _d; \
    Q4(r0, r1.x, _d) Q4(r1, r2.x, _d) Q4(r2, r3.x, _d) Q4(r3, r4.x, _d) \
    Q4(r4, r5.x, _d) Q4(r5, r6.x, _d) Q4(r6, r7.x, _d) Q4(r7, (PEEK), _d) }

__device__ __forceinline__ int swzg(int g) { return g ^ ((g >> 3) & 7); }

typedef __attribute__((address_space(1))) const unsigned int GBUF;
typedef __attribute__((address_space(3))) unsigned int LBUF;

// Issue 8 contiguous 1KB global_load_lds (source lane-permuted per rule #21).
#define STAGE(DST, XSRC) { \
    _Pragma("unroll") \
    for (int _i = 0; _i < 8; ++_i) \
        __builtin_amdgcn_global_load_lds((GBUF*)((XSRC) + _i * 256 + (lsrc << 2)), \
                                         (LBUF*)((DST) + _i * 256), 16, 0, 0); }

// Per-row constants, numpy-port op order; hoisted above all VMEM.
#define LOADC(IDX) \
    const int   ch_##IDX  = (wrow + (IDX)) & (C_ - 1); \
    const float w0_##IDX  = w[ch_##IDX * 3 + 0]; \
    const float w1_##IDX  = w[ch_##IDX * 3 + 1]; \
    const float w2_##IDX  = w[ch_##IDX * 3 + 2]; \
    const float bb_##IDX  = cb[ch_##IDX]; \
    const float sq_##IDX  = sqrtf(rvar[ch_##IDX] + 1e-5f); \
    const float rs_##IDX  = 1.0f / sq_##IDX; \
    const float inv_##IDX = gamma[ch_##IDX] * rs_##IDX; \
    const float add_##IDX = beta[ch_##IDX] - rmean[ch_##IDX] * inv_##IDX;

// R10/R12 scan body verbatim (bitwise-proven): scan + LDS writeback +
// coalesced 1 KB stores.
#define ROWBODY(IDX) { \
    const float w0 = w0_##IDX, w1 = w1_##IDX, w2 = w2_##IDX; \
    const float bb = bb_##IDX, inv = inv_##IDX, add = add_##IDX; \
    float* outr = outrow + (IDX) * T_; \
    const int G2  = 8 * l; \
    const int G1c = (l >= 1) ? G2 - 8  : 0; \
    const int G0c = (l >= 2) ? G2 - 16 : 0; \
    const int gt  = (l >= 3) ? (G2 - 17) : 0; \
    const f32x4 tail = *(const f32x4*)(wl + (swzg(gt) << 2)); \
    float xm1 = (l >= 3) ? tail.w : 0.0f; \
    float v = 0.0f; \
    f32x4 a0,a1,a2,a3,a4,a5,a6,a7; \
    f32x4 b0,b1,b2,b3,b4,b5,b6,b7; \
    f32x4 c0,c1,c2,c3,c4,c5,c6,c7; \
    LDPH(a0,a1,a2,a3,a4,a5,a6,a7, G0c) \
    LDPH(b0,b1,b2,b3,b4,b5,b6,b7, G1c) \
    c0 = *(const f32x4*)(wl + ((G2 + (0 ^ (l & 7))) << 2)); \
    if (l >= 2) { PHC(a0,a1,a2,a3,a4,a5,a6,a7, b0.x) } \
    { \
        const int _m = l & 7; \
        const float* _bp = wl + (G2 << 2); \
        c1 = *(const f32x4*)(_bp + ((1 ^ _m) << 2)); \
        c2 = *(const f32x4*)(_bp + ((2 ^ _m) << 2)); \
        c3 = *(const f32x4*)(_bp + ((3 ^ _m) << 2)); \
        c4 = *(const f32x4*)(_bp + ((4 ^ _m) << 2)); \
        c5 = *(const f32x4*)(_bp + ((5 ^ _m) << 2)); \
        c6 = *(const f32x4*)(_bp + ((6 ^ _m) << 2)); \
        c7 = *(const f32x4*)(_bp + ((7 ^ _m) << 2)); \
    } \
    const int gp = (l < 63) ? (G2 + 8) : 0; \
    const f32x4 pk = *(const f32x4*)(wl + (swzg(gp) << 2)); \
    const float peekOwn = (l == 63) ? 0.0f : pk.x; \
    if (l >= 1) { PHC(b0,b1,b2,b3,b4,b5,b6,b7, c0.x) } \
    f32x4 o0,o1,o2,o3,o4,o5,o6,o7; \
    Q4(c0, c1.x, o0) Q4(c1, c2.x, o1) Q4(c2, c3.x, o2) Q4(c3, c4.x, o3) \
    Q4(c4, c5.x, o4) Q4(c5, c6.x, o5) Q4(c6, c7.x, o6) Q4(c7, peekOwn, o7) \
    { \
        const int m8 = l & 7; \
        float* wb = wl + (G2 << 2); \
        *(f32x4*)(wb + ((0 ^ m8) << 2)) = o0; \
        *(f32x4*)(wb + ((1 ^ m8) << 2)) = o1; \
        *(f32x4*)(wb + ((2 ^ m8) << 2)) = o2; \
        *(f32x4*)(wb + ((3 ^ m8) << 2)) = o3; \
        *(f32x4*)(wb + ((4 ^ m8) << 2)) = o4; \
        *(f32x4*)(wb + ((5 ^ m8) << 2)) = o5; \
        *(f32x4*)(wb + ((6 ^ m8) << 2)) = o6; \
        *(f32x4*)(wb + ((7 ^ m8) << 2)) = o7; \
    } \
    _Pragma("unroll") \
    for (int _i = 0; _i < 8; ++_i) { \
        const f32x4 rb = *(const f32x4*)(wl + ((_i * 64 + lsrc) << 2)); \
        *(f32x4*)(outr + _i * 256 + (l << 2)) = rb; \
    } }

__global__ __launch_bounds__(128, 4) void cpe_lif_kernel(
    const float* __restrict__ x, const float* __restrict__ w,
    const float* __restrict__ cb, const float* __restrict__ gamma,
    const float* __restrict__ beta, const float* __restrict__ rmean,
    const float* __restrict__ rvar, float* __restrict__ out)
{
#pragma clang fp contract(off)   // match np reference rounding op-for-op
    __shared__ __align__(16) float lds[2 * T_];   // 16 KiB: one 8 KiB buf/wave

    const int tid = threadIdx.x;
    const int wid = __builtin_amdgcn_readfirstlane(tid >> 6);  // uniform
    const int l   = tid & 63;

    const int wrow = (blockIdx.x * 2 + wid) * 2;   // 2 consecutive rows/wave
    const float* xrow   = x   + (size_t)wrow * T_;
    float*       outrow = out + (size_t)wrow * T_;
    float*       wl     = lds + wid * T_;

    LOADC(0) LOADC(1)

    const int lsrc = l ^ ((l >> 3) & 7);

    // Row 0: DMA-stage into LDS.
    STAGE(wl, xrow)                                  // L0 x8 (vmcnt ops)
    __builtin_amdgcn_sched_barrier(0);

    // Row 1: reg-stage (T14). Same layout as STAGE: lane l loads global
    // granule i*64+lsrc -> later ds_write to LDS granule i*64+l.
    f32x4 p0,p1,p2,p3,p4,p5,p6,p7;
    {
        const float* xs = xrow + T_;
        p0 = *(const f32x4*)(xs + ((0 * 64 + lsrc) << 2));
        p1 = *(const f32x4*)(xs + ((1 * 64 + lsrc) << 2));
        p2 = *(const f32x4*)(xs + ((2 * 64 + lsrc) << 2));
        p3 = *(const f32x4*)(xs + ((3 * 64 + lsrc) << 2));
        p4 = *(const f32x4*)(xs + ((4 * 64 + lsrc) << 2));
        p5 = *(const f32x4*)(xs + ((5 * 64 + lsrc) << 2));
        p6 = *(const f32x4*)(xs + ((6 * 64 + lsrc) << 2));
        p7 = *(const f32x4*)(xs + ((7 * 64 + lsrc) << 2));
    }
    __builtin_amdgcn_sched_barrier(0);

    // FIFO: [L0(8), P1(8)] -> vmcnt(8) retires L0; P1 stays in flight.
    asm volatile("s_waitcnt vmcnt(8)" ::: "memory");
    __builtin_amdgcn_sched_barrier(0);

    ROWBODY(0)                                       // ends with stores S0

    // P1-reg -> ds_write edge is compiler-tracked (it inserts the counted
    // vmcnt for the p uses); fence just pins placement after S0.
    __builtin_amdgcn_sched_barrier(0);
    {   // overwrite buffer with row 1 (row 0 fully consumed; DS pipe in-order)
        *(f32x4*)(wl + ((0 * 64 + l) << 2)) = p0;
        *(f32x4*)(wl + ((1 * 64 + l) << 2)) = p1;
        *(f32x4*)(wl + ((2 * 64 + l) << 2)) = p2;
        *(f32x4*)(wl + ((3 * 64 + l) << 2)) = p3;
        *(f32x4*)(wl + ((4 * 64 + l) << 2)) = p4;
        *(f32x4*)(wl + ((5 * 64 + l) << 2)) = p5;
        *(f32x4*)(wl + ((6 * 64 + l) << 2)) = p6;
        *(f32x4*)(wl + ((7 * 64 + l) << 2)) = p7;
    }

    ROWBODY(1)
}

extern "C" void kernel_launch(void* const* d_in, const int* in_sizes, int n_in,
                              void* d_out, int out_size, void* d_ws, size_t ws_size,
                              hipStream_t stream) {
    const float* x     = (const float*)d_in[0];
    const float* w     = (const float*)d_in[1];
    const float* cb    = (const float*)d_in[2];
    const float* gamma = (const float*)d_in[3];
    const float* beta  = (const float*)d_in[4];
    const float* rmean = (const float*)d_in[5];
    const float* rvar  = (const float*)d_in[6];
    float* out = (float*)d_out;

    // 8192 rows / (2 rows/wave x 2 waves/block) = 2048 blocks.
    const int grid = (B_ * C_) / 4;
    cpe_lif_kernel<<<grid, 128, 0, stream>>>(x, w, cb, gamma, beta, rmean, rvar, out);
}

// Round 14
// 28.305 us; speedup vs baseline: 1.1227x; 1.1227x over previous
//
#include <hip/hip_runtime.h>

typedef float f32x4 __attribute__((ext_vector_type(4)));

// Problem constants: x [B,C,T] fp32 -> out [B,C,T] fp32.
#define B_ 32
#define C_ 256
#define T_ 2048
#define NR 4           // rows per wave

// R5:  plain stores (L2 write-combining), never nontemporal.
// R7:  strided global loads cap ~2.6 TB/s -> coalesced only.
// R8:  XOR-swizzled b128 LDS reads conflict-free.
// R10: coalesced stores via LDS round-trip: 40->31 us.
// R11-R13: pipelining/TLP/reg-staging variants all flat at 30-32 us; wave
//   vmem issue had multi-1000-cy gaps + gload_lds DMA opacity. R14: NO
//   global_load_lds anywhere; continuous per-wave issue: loads(r+1) at iter
//   start, vmcnt(0) only when all outstanding ops are >=2500cy old.

#define STEP(X0, XP1, O) { \
    float y = w0 * xm1;  y = y + w1 * (X0);  y = y + w2 * (XP1); \
    y = y + bb;  y = y * inv;  y = y + add; \
    float dv = (y - v) * 0.5f;  v = v + dv; \
    float s = (v >= 1.0f) ? 1.0f : 0.0f; \
    (O) = s + (X0); \
    v = (v >= 1.0f) ? 0.0f : v; \
    xm1 = (X0); }

#define Q4(BV, NX, O) \
    STEP(BV.x, BV.y, O.x) STEP(BV.y, BV.z, O.y) \
    STEP(BV.z, BV.w, O.z) STEP(BV.w, NX,   O.w)

#define LDPH(p0,p1,p2,p3,p4,p5,p6,p7, GC) { \
    const int _m = ((GC) >> 3) & 7; \
    const float* _bp = wl + ((GC) << 2); \
    p0 = *(const f32x4*)(_bp + ((0 ^ _m) << 2)); \
    p1 = *(const f32x4*)(_bp + ((1 ^ _m) << 2)); \
    p2 = *(const f32x4*)(_bp + ((2 ^ _m) << 2)); \
    p3 = *(const f32x4*)(_bp + ((3 ^ _m) << 2)); \
    p4 = *(const f32x4*)(_bp + ((4 ^ _m) << 2)); \
    p5 = *(const f32x4*)(_bp + ((5 ^ _m) << 2)); \
    p6 = *(const f32x4*)(_bp + ((6 ^ _m) << 2)); \
    p7 = *(const f32x4*)(_bp + ((7 ^ _m) << 2)); }

#define PHC(r0,r1,r2,r3,r4,r5,r6,r7, PEEK) { \
    f32x4 _d; \
    Q4(r0, r1.x, _d) Q4(r1, r2.x, _d) Q4(r2, r3.x, _d) Q4(r3, r4.x, _d) \
    Q4(r4, r5.x, _d) Q4(r5, r6.x, _d) Q4(r6, r7.x, _d) Q4(r7, (PEEK), _d) }

__device__ __forceinline__ int swzg(int g) { return g ^ ((g >> 3) & 7); }

// Coalesced reg-stage: lane l loads global granule i*64+lsrc (R13-proven).
#define PLOAD(XS) { \
    p0 = *(const f32x4*)((XS) + ((0 * 64 + lsrc) << 2)); \
    p1 = *(const f32x4*)((XS) + ((1 * 64 + lsrc) << 2)); \
    p2 = *(const f32x4*)((XS) + ((2 * 64 + lsrc) << 2)); \
    p3 = *(const f32x4*)((XS) + ((3 * 64 + lsrc) << 2)); \
    p4 = *(const f32x4*)((XS) + ((4 * 64 + lsrc) << 2)); \
    p5 = *(const f32x4*)((XS) + ((5 * 64 + lsrc) << 2)); \
    p6 = *(const f32x4*)((XS) + ((6 * 64 + lsrc) << 2)); \
    p7 = *(const f32x4*)((XS) + ((7 * 64 + lsrc) << 2)); }

// ds_write staged regs: LDS granule i*64+l gets global granule i*64+lsrc,
// i.e. LDS granule s holds global granule swzg(s) (R13-proven).
#define DSW() { \
    *(f32x4*)(wl + ((0 * 64 + l) << 2)) = p0; \
    *(f32x4*)(wl + ((1 * 64 + l) << 2)) = p1; \
    *(f32x4*)(wl + ((2 * 64 + l) << 2)) = p2; \
    *(f32x4*)(wl + ((3 * 64 + l) << 2)) = p3; \
    *(f32x4*)(wl + ((4 * 64 + l) << 2)) = p4; \
    *(f32x4*)(wl + ((5 * 64 + l) << 2)) = p5; \
    *(f32x4*)(wl + ((6 * 64 + l) << 2)) = p6; \
    *(f32x4*)(wl + ((7 * 64 + l) << 2)) = p7; }

// Per-row constants, numpy-port op order.
#define LOADC(IDX) \
    const int   ch_##IDX  = (wrow + (IDX)) & (C_ - 1); \
    const float w0_##IDX  = w[ch_##IDX * 3 + 0]; \
    const float w1_##IDX  = w[ch_##IDX * 3 + 1]; \
    const float w2_##IDX  = w[ch_##IDX * 3 + 2]; \
    const float bb_##IDX  = cb[ch_##IDX]; \
    const float sq_##IDX  = sqrtf(rvar[ch_##IDX] + 1e-5f); \
    const float rs_##IDX  = 1.0f / sq_##IDX; \
    const float inv_##IDX = gamma[ch_##IDX] * rs_##IDX; \
    const float add_##IDX = beta[ch_##IDX] - rmean[ch_##IDX] * inv_##IDX;

#define SEL4(NAME) ((r == 0) ? NAME##_0 : (r == 1) ? NAME##_1 : \
                    (r == 2) ? NAME##_2 : NAME##_3)

__global__ __launch_bounds__(128, 3) void cpe_lif_kernel(
    const float* __restrict__ x, const float* __restrict__ w,
    const float* __restrict__ cb, const float* __restrict__ gamma,
    const float* __restrict__ beta, const float* __restrict__ rmean,
    const float* __restrict__ rvar, float* __restrict__ out)
{
#pragma clang fp contract(off)   // match np reference rounding op-for-op
    __shared__ __align__(16) float lds[2 * T_];   // 16 KiB: one 8 KiB buf/wave

    const int tid = threadIdx.x;
    const int wid = __builtin_amdgcn_readfirstlane(tid >> 6);  // uniform
    const int l   = tid & 63;

    const int wrow = (blockIdx.x * 2 + wid) * NR;  // 4 consecutive rows/wave
    const float* xrow   = x   + (size_t)wrow * T_;
    float*       outrow = out + (size_t)wrow * T_;
    float*       wl     = lds + wid * T_;

    LOADC(0) LOADC(1) LOADC(2) LOADC(3)

    const int lsrc = l ^ ((l >> 3) & 7);

    f32x4 p0,p1,p2,p3,p4,p5,p6,p7;

    // Prologue: stage row 0 via registers (only exposed latency in the wave).
    PLOAD(xrow)
    __builtin_amdgcn_sched_barrier(0);
    asm volatile("s_waitcnt vmcnt(0)" ::: "memory");
    __builtin_amdgcn_sched_barrier(0);
    DSW()

#pragma clang loop unroll(disable)
    for (int r = 0; r < NR; ++r) {
        // (1) issue next row's loads immediately -> continuous vmem stream
        if (r + 1 < NR) { PLOAD(xrow + (size_t)(r + 1) * T_) }
        __builtin_amdgcn_sched_barrier(0);

        const float w0 = SEL4(w0), w1 = SEL4(w1), w2 = SEL4(w2);
        const float bb = SEL4(bb), inv = SEL4(inv), add = SEL4(add);
        float* outr = outrow + (size_t)r * T_;

        // (2) scan row r from LDS (R10/R12 body, bitwise-proven)
        const int G2  = 8 * l;
        const int G1c = (l >= 1) ? G2 - 8  : 0;
        const int G0c = (l >= 2) ? G2 - 16 : 0;
        const int gt  = (l >= 3) ? (G2 - 17) : 0;
        const f32x4 tail = *(const f32x4*)(wl + (swzg(gt) << 2));
        float xm1 = (l >= 3) ? tail.w : 0.0f;
        float v = 0.0f;

        f32x4 a0,a1,a2,a3,a4,a5,a6,a7;
        f32x4 b0,b1,b2,b3,b4,b5,b6,b7;
        f32x4 c0,c1,c2,c3,c4,c5,c6,c7;

        LDPH(a0,a1,a2,a3,a4,a5,a6,a7, G0c)
        LDPH(b0,b1,b2,b3,b4,b5,b6,b7, G1c)
        c0 = *(const f32x4*)(wl + ((G2 + (0 ^ (l & 7))) << 2));

        if (l >= 2) { PHC(a0,a1,a2,a3,a4,a5,a6,a7, b0.x) }

        {
            const int _m = l & 7;
            const float* _bp = wl + (G2 << 2);
            c1 = *(const f32x4*)(_bp + ((1 ^ _m) << 2));
            c2 = *(const f32x4*)(_bp + ((2 ^ _m) << 2));
            c3 = *(const f32x4*)(_bp + ((3 ^ _m) << 2));
            c4 = *(const f32x4*)(_bp + ((4 ^ _m) << 2));
            c5 = *(const f32x4*)(_bp + ((5 ^ _m) << 2));
            c6 = *(const f32x4*)(_bp + ((6 ^ _m) << 2));
            c7 = *(const f32x4*)(_bp + ((7 ^ _m) << 2));
        }
        const int gp = (l < 63) ? (G2 + 8) : 0;
        const f32x4 pk = *(const f32x4*)(wl + (swzg(gp) << 2));
        const float peekOwn = (l == 63) ? 0.0f : pk.x;

        if (l >= 1) { PHC(b0,b1,b2,b3,b4,b5,b6,b7, c0.x) }

        f32x4 o0,o1,o2,o3,o4,o5,o6,o7;
        Q4(c0, c1.x, o0) Q4(c1, c2.x, o1) Q4(c2, c3.x, o2) Q4(c3, c4.x, o3)
        Q4(c4, c5.x, o4) Q4(c5, c6.x, o5) Q4(c6, c7.x, o6) Q4(c7, peekOwn, o7)

        {   // LDS writeback (swzg bijection; wave-private slice)
            const int m8 = l & 7;
            float* wb = wl + (G2 << 2);
            *(f32x4*)(wb + ((0 ^ m8) << 2)) = o0;
            *(f32x4*)(wb + ((1 ^ m8) << 2)) = o1;
            *(f32x4*)(wb + ((2 ^ m8) << 2)) = o2;
            *(f32x4*)(wb + ((3 ^ m8) << 2)) = o3;
            *(f32x4*)(wb + ((4 ^ m8) << 2)) = o4;
            *(f32x4*)(wb + ((5 ^ m8) << 2)) = o5;
            *(f32x4*)(wb + ((6 ^ m8) << 2)) = o6;
            *(f32x4*)(wb + ((7 ^ m8) << 2)) = o7;
        }

        // (3) readback outputs to regs (coalescing transpose)
        f32x4 q0 = *(const f32x4*)(wl + ((0 * 64 + lsrc) << 2));
        f32x4 q1 = *(const f32x4*)(wl + ((1 * 64 + lsrc) << 2));
        f32x4 q2 = *(const f32x4*)(wl + ((2 * 64 + lsrc) << 2));
        f32x4 q3 = *(const f32x4*)(wl + ((3 * 64 + lsrc) << 2));
        f32x4 q4 = *(const f32x4*)(wl + ((4 * 64 + lsrc) << 2));
        f32x4 q5 = *(const f32x4*)(wl + ((5 * 64 + lsrc) << 2));
        f32x4 q6 = *(const f32x4*)(wl + ((6 * 64 + lsrc) << 2));
        f32x4 q7 = *(const f32x4*)(wl + ((7 * 64 + lsrc) << 2));

        // (4) drain: everything outstanding is >=1 scan old -> near-zero stall
        __builtin_amdgcn_sched_barrier(0);
        asm volatile("s_waitcnt vmcnt(0)" ::: "memory");
        __builtin_amdgcn_sched_barrier(0);

        // (5) overwrite LDS with row r+1 (row r fully consumed; DS in-order)
        if (r + 1 < NR) { DSW() }

        // (6) coalesced stores, fire-and-forget
        *(f32x4*)(outr + 0 * 256 + (l << 2)) = q0;
        *(f32x4*)(outr + 1 * 256 + (l << 2)) = q1;
        *(f32x4*)(outr + 2 * 256 + (l << 2)) = q2;
        *(f32x4*)(outr + 3 * 256 + (l << 2)) = q3;
        *(f32x4*)(outr + 4 * 256 + (l << 2)) = q4;
        *(f32x4*)(outr + 5 * 256 + (l << 2)) = q5;
        *(f32x4*)(outr + 6 * 256 + (l << 2)) = q6;
        *(f32x4*)(outr + 7 * 256 + (l << 2)) = q7;
    }
}

extern "C" void kernel_launch(void* const* d_in, const int* in_sizes, int n_in,
                              void* d_out, int out_size, void* d_ws, size_t ws_size,
                              hipStream_t stream) {
    const float* x     = (const float*)d_in[0];
    const float* w     = (const float*)d_in[1];
    const float* cb    = (const float*)d_in[2];
    const float* gamma = (const float*)d_in[3];
    const float* beta  = (const float*)d_in[4];
    const float* rmean = (const float*)d_in[5];
    const float* rvar  = (const float*)d_in[6];
    float* out = (float*)d_out;

    // 8192 rows / (NR=4 rows/wave x 2 waves/block) = 1024 blocks.
    const int grid = (B_ * C_) / (NR * 2);
    cpe_lif_kernel<<<grid, 128, 0, stream>>>(x, w, cb, gamma, beta, rmean, rvar, out);
}